// Round 8
// baseline (154.692 us; speedup 1.0000x reference)
//
#include <hip/hip_runtime.h>
#include <hip/hip_bf16.h>
#include <cstdint>

// ---------------------------------------------------------------------------
// CausalSelfAttention: x@Wqkv+b -> heads -> causal flash attn -> @Wproj+b
// B=2 T=2048 C=1024 H=16 Dh=64.
// R18: certainty package (counters blinded by harness fill @42us).
//  - prep: W-transpose tiles 32k x 128n, float4 loads (was 4B scalar),
//    uint4 stores (16B/lane, was 2B scalar u16!). grid 5120.
//  - gemm_qkv: 2x2 wave arrangement (wave tile 64x96, acc[4][6]): 20 LDS
//    reads/tile vs 22 (A-frags duplicated 2x not 4x).
//  - gemm_qkv: VF epilogue packs r=0..3 (consecutive u16) into uint2 via
//    cvtpk -> 24 stores/thread instead of 96.
// R17 (kept): 2 independently-phased blocks/CU both GEMMs (m114 overlap);
//  1-phase body, counted vmcnt, granule XOR-swizzle (conflicts 0).
// R14 (kept): attn uniform-wave (63-u then u), K+V depth-2 ping-pong,
//  l via ones-MFMA, cvt_pk pack. Attn occupancy is GRID-limited (1024
//  blocks x 2 waves = 2/SIMD); finer split doubles L2 KV traffic.
// HARD-WON NOTES:
//  - R7: forcing low VGPR -> catastrophic spills.
//  - R13: VGPR>128 cliff; occupancy-DECAY from non-uniform blocks dominates.
//  - R11: partial-coverage grids idle CUs; coverage before tile size.
//  - R15/R16: schedule tuning inside ONE barrier-locked block is futile;
//    independent co-resident blocks overlap mem and MFMA phases.
// ---------------------------------------------------------------------------

using u16 = unsigned short;
using u32 = unsigned int;

typedef __bf16 bf16x8 __attribute__((ext_vector_type(8)));
typedef float f32x4 __attribute__((ext_vector_type(4)));

#define AS1 __attribute__((address_space(1)))
#define AS3 __attribute__((address_space(3)))

__device__ __forceinline__ u16 f2bf(float f) {
  u32 u = __float_as_uint(f);
  u += 0x7fffu + ((u >> 16) & 1u);   // RTNE
  return (u16)(u >> 16);
}
__device__ __forceinline__ u32 cvtpk(float a, float b) {
  u32 r;
  asm("v_cvt_pk_bf16_f32 %0, %1, %2" : "=v"(r) : "v"(a), "v"(b));
  return r;
}

// ---------------- prep: cvt x->bf16 (blocks 0..4095) + W transposes ---------
// W-transpose: blocks 4096..5119. 1024 blocks = 32 n-tiles(128) x 32 k-tiles
// (32). float4 loads, LDS transpose, uint4 (8xbf16) stores.
__global__ __launch_bounds__(256) void prep(const float* __restrict__ x,
                                            u16* __restrict__ xb,
                                            const float* __restrict__ W0,
                                            u16* __restrict__ T0,
                                            const float* __restrict__ W1,
                                            u16* __restrict__ T1) {
  const int bx = blockIdx.x;
  const int tid = threadIdx.x;
  if (bx < 4096) {
    const int i = bx * 256 + tid;
    float4 v = ((const float4*)x)[i];
    ushort4 o;
    o.x = f2bf(v.x); o.y = f2bf(v.y); o.z = f2bf(v.z); o.w = f2bf(v.w);
    ((ushort4*)xb)[i] = o;
    return;
  }
  __shared__ float t[32][129];
  const int idx = bx - 4096;                 // 32 n-tiles x 32 k-tiles
  const int nti = idx & 31, kti = idx >> 5;
  const float* W; u16* Wt; int N, n0;
  if (nti < 24) { W = W0; Wt = T0; N = 3072; n0 = nti * 128; }
  else          { W = W1; Wt = T1; N = 1024; n0 = (nti - 24) * 128; }
  const int k0 = kti * 32;

  // load: 8 k-rows per pass x 32 float4 cols; 4 passes
  const int kr = tid >> 5, nc = (tid & 31) * 4;
#pragma unroll
  for (int i = 0; i < 4; ++i) {
    const float4 v = *(const float4*)&W[(size_t)(k0 + kr + i * 8) * N + n0 + nc];
    t[kr + i * 8][nc + 0] = v.x;
    t[kr + i * 8][nc + 1] = v.y;
    t[kr + i * 8][nc + 2] = v.z;
    t[kr + i * 8][nc + 3] = v.w;
  }
  __syncthreads();
  // store: r = tid>>1 (128 n-rows), kc = (tid&1)*16; 2x 8-elem uint4 stores
  const int r = tid >> 1, kc = (tid & 1) * 16;
#pragma unroll
  for (int h = 0; h < 2; ++h) {
    union { u32 w[4]; uint4 v; } o;
#pragma unroll
    for (int jj = 0; jj < 4; ++jj) {
      const u16 lo = f2bf(t[kc + h * 8 + jj * 2 + 0][r]);
      const u16 hi = f2bf(t[kc + h * 8 + jj * 2 + 1][r]);
      o.w[jj] = (u32)lo | ((u32)hi << 16);
    }
    *(uint4*)&Wt[(size_t)(n0 + r) * 1024 + k0 + kc + h * 8] = o.v;
  }
}

// ---------------- QKV GEMM: 128x192, 2 blocks/CU, 1-phase, 2x2 waves --------
// n<1024: Q (scaled by cs) -> qb[4096][1024]
// 1024<=n<2048: K -> KF fragment order [bh][kt][m][hh][lane][8]
// n>=2048:     V -> VF fragment order [bh][kt][hh][di][lane][8] (k-permuted)
#define MFMA16 __builtin_amdgcn_mfma_f32_16x16x32_bf16

__global__ __launch_bounds__(256, 2) void gemm_qkv(const u16* __restrict__ A,
                                                   const u16* __restrict__ Bt,
                                                   const float* __restrict__ bias,
                                                   u16* __restrict__ qb,
                                                   u16* __restrict__ KF,
                                                   u16* __restrict__ VF,
                                                   float sc_val) {
  constexpr int NT = 16;                    // K=1024 / BK=64
  constexpr int BUFO = 5 * 4096;            // u16 per buffer (A0,A1,B0,B1,B2)
  __shared__ __align__(16) u16 sm[2 * BUFO];  // 80 KiB -> 2 blocks/CU

  const int tid  = threadIdx.x;
  const int lane = tid & 63;
  const int w    = tid >> 6;          // 0..3
  const int quad = lane >> 4;
  const int l15  = lane & 15;

  // block -> tile: 512 blocks = 8 XCD x 64; each XCD: 4 mt x 16 nt
  const int bid = blockIdx.x;
  const int xcd = bid & 7, c = bid >> 3;     // c 0..63
  const int mt = xcd * 4 + (c & 3);          // 0..31
  const int nt = c >> 2;                     // 0..15
  const int bm = mt * 128, bn = nt * 192;

  // 2x2 wave arrangement: wave tile 64 rows x 96 cols (A dup 2x, was 4x)
  const int wr = (w >> 1) * 64;       // wave rows (0/64)
  const int wc = (w & 1) * 96;        // wave cols (0/96)

  // ---- staging: thread writes 16B linearly at chunk + tid*16 (2 halves).
  const int srow = tid >> 3;          // 0..31
  const int scol = (((tid & 7) ^ ((tid >> 3) & 7)) << 3);

#define STAGEA(ch, ktile, bufo)                                                 \
  do {                                                                          \
    const u16* _s = A + (size_t)(bm + (ch) * 64 + srow) * 1024 +                \
                    ((ktile) << 6) + scol;                                      \
    u16* _d = sm + (bufo) + (ch) * 4096 + tid * 8;                              \
    __builtin_amdgcn_global_load_lds((AS1 const void*)_s, (AS3 void*)_d,        \
                                     16, 0, 0);                                 \
    __builtin_amdgcn_global_load_lds((AS1 const void*)(_s + (32 << 10)),        \
                                     (AS3 void*)(_d + 2048), 16, 0, 0);         \
  } while (0)
#define STAGEB(ch, ktile, bufo)                                                 \
  do {                                                                          \
    const u16* _s = Bt + (size_t)(bn + (ch) * 64 + srow) * 1024 +               \
                    ((ktile) << 6) + scol;                                      \
    u16* _d = sm + (bufo) + (2 + (ch)) * 4096 + tid * 8;                        \
    __builtin_amdgcn_global_load_lds((AS1 const void*)_s, (AS3 void*)_d,        \
                                     16, 0, 0);                                 \
    __builtin_amdgcn_global_load_lds((AS1 const void*)(_s + (32 << 10)),        \
                                     (AS3 void*)(_d + 2048), 16, 0, 0);         \
  } while (0)

  // ---- ds-read bases (swizzled granule; row&7 == l15&7: wr,wc,16ni ≡0 mod 8)
  int abase[4], bbase[6];
#pragma unroll
  for (int mi = 0; mi < 4; ++mi)
    abase[mi] = (wr >> 6) * 4096 + (mi * 16 + l15) * 64;
#pragma unroll
  for (int ni = 0; ni < 6; ++ni) {
    const int rb = wc + ni * 16 + l15;                  // 0..191
    bbase[ni] = (2 + (rb >> 6)) * 4096 + (rb & 63) * 64;
  }
  const int sw0 = ((quad ^ (l15 & 7)) << 3);
  const int sw1 = sw0 ^ 32;

  // ---- prologue: kt0 all 5 -> buf0 (10 issues); A01(kt1) -> buf1 (4)
  STAGEA(0, 0, 0); STAGEA(1, 0, 0);
  STAGEB(0, 0, 0); STAGEB(1, 0, 0); STAGEB(2, 0, 0);
  STAGEA(0, 1, BUFO); STAGEA(1, 1, BUFO);
  asm volatile("s_waitcnt vmcnt(4)" ::: "memory");  // kt0's 10 landed
  __builtin_amdgcn_s_barrier();

  f32x4 acc[4][6] = {};
  bf16x8 a[4][2], b[6][2];

#pragma unroll 2
  for (int j = 0; j < NT; ++j) {
    const int bo  = (j & 1) * BUFO;
    const int nbo = bo ^ BUFO;
    const u16* smb = sm + bo;

    // ---- issue ALL 20 ds_reads (buf j fully landed): A(8), b01(4), b2-5(8)
#pragma unroll
    for (int mi = 0; mi < 4; ++mi) {
      a[mi][0] = *(const bf16x8*)(smb + abase[mi] + sw0);
      a[mi][1] = *(const bf16x8*)(smb + abase[mi] + sw1);
    }
#pragma unroll
    for (int ni = 0; ni < 2; ++ni) {
      b[ni][0] = *(const bf16x8*)(smb + bbase[ni] + sw0);
      b[ni][1] = *(const bf16x8*)(smb + bbase[ni] + sw1);
    }
#pragma unroll
    for (int ni = 2; ni < 6; ++ni) {
      b[ni][0] = *(const bf16x8*)(smb + bbase[ni] + sw0);
      b[ni][1] = *(const bf16x8*)(smb + bbase[ni] + sw1);
    }
    // stage B(j+1) -> other buffer (its B chunks drained in tile j-1)
    if (j + 1 < NT) { STAGEB(0, j + 1, nbo); STAGEB(1, j + 1, nbo); STAGEB(2, j + 1, nbo); }

    asm volatile("s_waitcnt lgkmcnt(8)" ::: "memory");   // A + b01 (12) landed
    __builtin_amdgcn_sched_barrier(0);
    __builtin_amdgcn_s_setprio(1);
    // MFMA grp0: A x b01 (reads 13-20 complete underneath)
#pragma unroll
    for (int mi = 0; mi < 4; ++mi)
#pragma unroll
      for (int ni = 0; ni < 2; ++ni) {
        acc[mi][ni] = MFMA16(a[mi][0], b[ni][0], acc[mi][ni], 0, 0, 0);
        acc[mi][ni] = MFMA16(a[mi][1], b[ni][1], acc[mi][ni], 0, 0, 0);
      }
    __builtin_amdgcn_s_setprio(0);
    asm volatile("s_waitcnt lgkmcnt(0)" ::: "memory");   // all 20 landed
    __builtin_amdgcn_sched_barrier(0);
    __builtin_amdgcn_s_barrier();     // every wave done READING buf j
    // stage A(j+2) -> CURRENT buffer (safe: reads retired to registers)
    if (j + 2 < NT) { STAGEA(0, j + 2, bo); STAGEA(1, j + 2, bo); }
    __builtin_amdgcn_s_setprio(1);
    // MFMA grp1 (register-only; runs over the staging writes)
#pragma unroll
    for (int mi = 0; mi < 4; ++mi)
#pragma unroll
      for (int ni = 2; ni < 6; ++ni) {
        acc[mi][ni] = MFMA16(a[mi][0], b[ni][0], acc[mi][ni], 0, 0, 0);
        acc[mi][ni] = MFMA16(a[mi][1], b[ni][1], acc[mi][ni], 0, 0, 0);
      }
    __builtin_amdgcn_s_setprio(0);
    if (j + 2 < NT)
      asm volatile("s_waitcnt vmcnt(4)" ::: "memory"); // A(j+1)+B(j+1) landed
    else
      asm volatile("s_waitcnt vmcnt(0)" ::: "memory"); // tail drain
    __builtin_amdgcn_s_barrier();
  }
#undef STAGEA
#undef STAGEB

  // ---- epilogue: per-ni region branch (192-wide blocks straddle Q/K/V) ----
  const int crow0 = bm + wr + (quad << 2);
  const int ccol0 = bn + wc + l15;
#pragma unroll
  for (int ni = 0; ni < 6; ++ni) {
    const int n = ccol0 + ni * 16;
    const float bv = bias[n];
    if (n < 1024) {                     // ---- Q (scaled) ----
#pragma unroll
      for (int mi = 0; mi < 4; ++mi) {
        const int m0 = crow0 + mi * 16;
#pragma unroll
        for (int r = 0; r < 4; ++r)
          qb[(size_t)(m0 + r) * 1024 + n] = f2bf((acc[mi][ni][r] + bv) * sc_val);
      }
    } else if (n < 2048) {              // ---- K fragment order ----
      const int hk = (n - 1024) >> 6;
      const int d  = (n - 1024) & 63;
      const int hh = d >> 5, qd = (d >> 3) & 3, jj = d & 7;
#pragma unroll
      for (int mi = 0; mi < 4; ++mi) {
#pragma unroll
        for (int r = 0; r < 4; ++r) {
          const int t  = crow0 + mi * 16 + r;
          const int bb = t >> 11, tt = t & 2047;
          const int kt = tt >> 6, mm = (tt >> 4) & 3, l = tt & 15;
          KF[((size_t)((bb * 16 + hk) * 32 + kt) * 8 + mm * 2 + hh) * 512 +
             (qd * 16 + l) * 8 + jj] = f2bf(acc[mi][ni][r] + bv);
        }
      }
    } else {                            // ---- V fragment order (k-perm) ----
      // r=0..3 -> consecutive u16 (jj=(mq&1)*4+r, crow0%4==0): 8B packed store
      const int hv = (n - 2048) >> 6;
      const int d  = (n - 2048) & 63;
      const int di = d >> 4, l = d & 15;
#pragma unroll
      for (int mi = 0; mi < 4; ++mi) {
        const int t  = crow0 + mi * 16;          // r=0 row (t%4 == 0)
        const int bb = t >> 11, tt = t & 2047;
        const int kt = tt >> 6, to = tt & 63;
        const int mq = to >> 4, qd2 = (to >> 2) & 3;
        const int hh = mq >> 1, jj = (mq & 1) * 4;
        uint2 o;
        o.x = cvtpk(acc[mi][ni][0] + bv, acc[mi][ni][1] + bv);
        o.y = cvtpk(acc[mi][ni][2] + bv, acc[mi][ni][3] + bv);
        *(uint2*)&VF[((size_t)((bb * 16 + hv) * 32 + kt) * 8 + hh * 4 + di) * 512 +
                     (qd2 * 16 + l) * 8 + jj] = o;
      }
    }
  }
}

// ---------------- Proj GEMM: 128x64, 2 blocks/CU, 1-phase -------------------
// M=4096 N=1024 K=1024, fp32 out.  512 blocks (32 mt x 16 nt), 256 thr,
// 4 waves @ 64x32 (acc[4][2]).  LDS 2 bufs x {A0,A1,B0} = 48 KiB.
__global__ __launch_bounds__(256, 2) void gemm_proj(const u16* __restrict__ A,
                                                    const u16* __restrict__ Bt,
                                                    const float* __restrict__ bias,
                                                    float* __restrict__ C) {
  constexpr int NT = 16;                    // K=1024 / BK=64
  constexpr int BUFO = 3 * 4096;            // u16 per buffer (A0,A1,B0)
  __shared__ __align__(16) u16 sm[2 * BUFO];  // 48 KiB

  const int tid  = threadIdx.x;
  const int lane = tid & 63;
  const int w    = tid >> 6;          // 0..3
  const int quad = lane >> 4;
  const int l15  = lane & 15;

  // 512 blocks = 8 XCD x 64: each XCD 4 mt x 16 nt
  const int bid = blockIdx.x;
  const int xcd = bid & 7, c = bid >> 3;     // c 0..63
  const int mt = xcd * 4 + (c & 3);          // 0..31
  const int nt = c >> 2;                     // 0..15
  const int bm = mt * 128, bn = nt * 64;

  const int wr = (w >> 1) * 64;       // wave rows (0/64)
  const int wcC = (w & 1) * 32;       // wave cols (0/32)

  const int srow = tid >> 3;
  const int scol = (((tid & 7) ^ ((tid >> 3) & 7)) << 3);

#define PSTAGEA(ch, ktile, bufo)                                                \
  do {                                                                          \
    const u16* _s = A + (size_t)(bm + (ch) * 64 + srow) * 1024 +                \
                    ((ktile) << 6) + scol;                                      \
    u16* _d = sm + (bufo) + (ch) * 4096 + tid * 8;                              \
    __builtin_amdgcn_global_load_lds((AS1 const void*)_s, (AS3 void*)_d,        \
                                     16, 0, 0);                                 \
    __builtin_amdgcn_global_load_lds((AS1 const void*)(_s + (32 << 10)),        \
                                     (AS3 void*)(_d + 2048), 16, 0, 0);         \
  } while (0)
#define PSTAGEB(ktile, bufo)                                                    \
  do {                                                                          \
    const u16* _s = Bt + (size_t)(bn + srow) * 1024 + ((ktile) << 6) + scol;    \
    u16* _d = sm + (bufo) + 2 * 4096 + tid * 8;                                 \
    __builtin_amdgcn_global_load_lds((AS1 const void*)_s, (AS3 void*)_d,        \
                                     16, 0, 0);                                 \
    __builtin_amdgcn_global_load_lds((AS1 const void*)(_s + (32 << 10)),        \
                                     (AS3 void*)(_d + 2048), 16, 0, 0);         \
  } while (0)

  int abase[4], bbase[2];
#pragma unroll
  for (int mi = 0; mi < 4; ++mi)
    abase[mi] = (w >> 1) * 4096 + (mi * 16 + l15) * 64;
#pragma unroll
  for (int ni = 0; ni < 2; ++ni)
    bbase[ni] = 2 * 4096 + (wcC + ni * 16 + l15) * 64;
  const int sw0 = ((quad ^ (l15 & 7)) << 3);
  const int sw1 = sw0 ^ 32;

  // prologue: kt0 {A0,A1,B0} -> buf0 (6); A01(kt1) -> buf1 (4)
  PSTAGEA(0, 0, 0); PSTAGEA(1, 0, 0); PSTAGEB(0, 0);
  PSTAGEA(0, 1, BUFO); PSTAGEA(1, 1, BUFO);
  asm volatile("s_waitcnt vmcnt(4)" ::: "memory");  // kt0's 6 landed
  __builtin_amdgcn_s_barrier();

  f32x4 acc[4][2] = {};
  bf16x8 a[4][2], b[2][2];

#pragma unroll 2
  for (int j = 0; j < NT; ++j) {
    const int bo  = (j & 1) * BUFO;
    const int nbo = bo ^ BUFO;
    const u16* smb = sm + bo;

    // ---- issue ALL 12 ds_reads; stage B(j+1)->other ----
#pragma unroll
    for (int mi = 0; mi < 4; ++mi) {
      a[mi][0] = *(const bf16x8*)(smb + abase[mi] + sw0);
      a[mi][1] = *(const bf16x8*)(smb + abase[mi] + sw1);
    }
#pragma unroll
    for (int ni = 0; ni < 2; ++ni) {
      b[ni][0] = *(const bf16x8*)(smb + bbase[ni] + sw0);
      b[ni][1] = *(const bf16x8*)(smb + bbase[ni] + sw1);
    }
    if (j + 1 < NT) PSTAGEB(j + 1, nbo);

    asm volatile("s_waitcnt lgkmcnt(2)" ::: "memory");   // a + b0 landed
    __builtin_amdgcn_sched_barrier(0);
    __builtin_amdgcn_s_setprio(1);
#pragma unroll
    for (int mi = 0; mi < 4; ++mi) {
      acc[mi][0] = MFMA16(a[mi][0], b[0][0], acc[mi][0], 0, 0, 0);
      acc[mi][0] = MFMA16(a[mi][1], b[0][1], acc[mi][0], 0, 0, 0);
    }
    __builtin_amdgcn_s_setprio(0);
    asm volatile("s_waitcnt lgkmcnt(0)" ::: "memory");   // all 12 landed
    __builtin_amdgcn_sched_barrier(0);
    __builtin_amdgcn_s_barrier();     // every wave done READING buf j
    if (j + 2 < NT) { PSTAGEA(0, j + 2, bo); PSTAGEA(1, j + 2, bo); }
    __builtin_amdgcn_s_setprio(1);
#pragma unroll
    for (int mi = 0; mi < 4; ++mi) {
      acc[mi][1] = MFMA16(a[mi][0], b[1][0], acc[mi][1], 0, 0, 0);
      acc[mi][1] = MFMA16(a[mi][1], b[1][1], acc[mi][1], 0, 0, 0);
    }
    __builtin_amdgcn_s_setprio(0);
    if (j + 2 < NT)
      asm volatile("s_waitcnt vmcnt(4)" ::: "memory"); // A(j+1)+B(j+1) landed
    else
      asm volatile("s_waitcnt vmcnt(0)" ::: "memory"); // tail drain
    __builtin_amdgcn_s_barrier();
  }
#undef PSTAGEA
#undef PSTAGEB

  const int crow0 = bm + wr + (quad << 2);
  const int ccol0 = bn + wcC + l15;
#pragma unroll
  for (int ni = 0; ni < 2; ++ni) {
    const int n = ccol0 + ni * 16;
    const float bv = bias[n];
#pragma unroll
    for (int mi = 0; mi < 4; ++mi) {
      const int m0 = crow0 + mi * 16;
#pragma unroll
      for (int r = 0; r < 4; ++r)
        C[(size_t)(m0 + r) * 1024 + n] = acc[mi][ni][r] + bv;
    }
  }
}

// ---------------- uniform-wave pipelined MFMA flash attention ---------------
// grid 1024 x 128 threads.  bid: xcd = bid&7 (4 bh per XCD, KV L2-resident);
// c = bid>>3: u = c&31 (q-group pair), bh = xcd | ((c>>5)<<3).
// Each wave: q-group 63-u fully, then q-group u (accO reused between groups).
// Parity waves split kt; per-wave total = 16-17 tiles UNIFORMLY across the
// whole grid -> 2 waves/SIMD resident for the entire kernel, no decay.
// K AND V prefetched depth-2 (kA/kB, vA/vB static ping-pong).
__global__ __launch_bounds__(128, 2) void attn_bal(const u16* __restrict__ qb,
                                                   const u16* __restrict__ KF,
                                                   const u16* __restrict__ VF,
                                                   u16* __restrict__ out) {
  const int bid = blockIdx.x;
  const int c   = bid >> 3;
  const int u   = c & 31;
  const int bh  = (bid & 7) | ((c >> 5) << 3);
  const int b = bh >> 4, h = bh & 15;
  const int tid = threadIdx.x;
  const int lane = tid & 63;
  const int par  = tid >> 6;          // wave 0/1 = kt parity
  const int quad = lane >> 4;
  const int l15  = lane & 15;

  __shared__ float CB[64][41];        // [lane][32 accO + 8 accL], stride 41

  const u16* qbase = qb + (size_t)b * 2048 * 1024 + h * 64;
  const size_t fb = (size_t)bh * 32 * 4096 + lane * 8;
  const u16* kfb = KF + fb;
  const u16* vfb = VF + fb;

  union { u32 u4[4]; bf16x8 v; } onesu;
  onesu.u4[0] = onesu.u4[1] = onesu.u4[2] = onesu.u4[3] = 0x3f803f80u;
  const bf16x8 onesf = onesu.v;       // bf16 1.0 x8

  u16* const outb = out + (size_t)b * 2048 * 1024 + h * 64 + l15;

  auto run_group = [&](int g32) {
    const int q0 = g32 * 32;
    const int ktmax = g32 >> 1;

    // Q B-frags for this group
    bf16x8 qf[2][2];
#pragma unroll
    for (int g = 0; g < 2; ++g)
#pragma unroll
      for (int hh = 0; hh < 2; ++hh)
        qf[g][hh] = *(const bf16x8*)(qbase + (size_t)(q0 + g * 16 + l15) * 1024 +
                                     hh * 32 + quad * 8);

    f32x4 accO[2][4] = {};            // [g][di]: q=quad*4+r, d=di*16+l15
    f32x4 accL[2] = {};               // [g]: l for q=quad*4+r

    // depth-2 K+V pipeline, two register sets (static ping-pong, no rotate)
    bf16x8 kA[4][2], kB[4][2], vA[2][4], vB[2][4];
    {
      const u16* kp = kfb + (size_t)par * 4096;
      const u16* vp = vfb + (size_t)par * 4096;
#pragma unroll
      for (int m = 0; m < 4; ++m)
#pragma unroll
        for (int hh = 0; hh < 2; ++hh)
          kA[m][hh] = *(const bf16x8*)(kp + (m * 2 + hh) * 512);
#pragma unroll
      for (int hh = 0; hh < 2; ++hh)
#pragma unroll
        for (int di = 0; di < 4; ++di)
          vA[hh][di] = *(const bf16x8*)(vp + (hh * 4 + di) * 512);
    }

    auto tile = [&](int kt, bf16x8 (&KC)[4][2], bf16x8 (&KN)[4][2],
                    bf16x8 (&VC)[2][4], bf16x8 (&VN)[2][4]) {
      // prefetch kt+2 (clamped) into the other register set
      const int ktn = (kt + 2 <= ktmax) ? kt + 2 : ktmax;
      const u16* kpn = kfb + (size_t)ktn * 4096;
      const u16* vpn = vfb + (size_t)ktn * 4096;
#pragma unroll
      for (int m = 0; m < 4; ++m)
#pragma unroll
        for (int hh = 0; hh < 2; ++hh)
          KN[m][hh] = *(const bf16x8*)(kpn + (m * 2 + hh) * 512);
#pragma unroll
      for (int hh = 0; hh < 2; ++hh)
#pragma unroll
        for (int di = 0; di < 4; ++di)
          VN[hh][di] = *(const bf16x8*)(vpn + (hh * 4 + di) * 512);

      const bool diag = (kt == ktmax);
      bf16x8 ap[2][2];
#pragma unroll
      for (int g = 0; g < 2; ++g) {
        f32x4 sT[4] = {};
#pragma unroll
        for (int m = 0; m < 4; ++m) {
          sT[m] = MFMA16(KC[m][0], qf[g][0], sT[m], 0, 0, 0);
          sT[m] = MFMA16(KC[m][1], qf[g][1], sT[m], 0, 0, 0);
        }
        float pv[4][4];
        if (diag) {                    // only the last tile pays mask ops
          const int qgl = q0 + g * 16 + l15;
#pragma unroll
          for (int m = 0; m < 4; ++m)
#pragma unroll
            for (int r = 0; r < 4; ++r) {
              const bool msk = (kt * 64 + m * 16 + quad * 4 + r) > qgl;
              pv[m][r] = msk ? 0.f : __builtin_amdgcn_exp2f(sT[m][r]);
            }
        } else {
#pragma unroll
          for (int m = 0; m < 4; ++m)
#pragma unroll
            for (int r = 0; r < 4; ++r)
              pv[m][r] = __builtin_amdgcn_exp2f(sT[m][r]);
        }
        union { u32 u4[4]; bf16x8 v; } t0, t1;
        t0.u4[0] = cvtpk(pv[0][0], pv[0][1]);
        t0.u4[1] = cvtpk(pv[0][2], pv[0][3]);
        t0.u4[2] = cvtpk(pv[1][0], pv[1][1]);
        t0.u4[3] = cvtpk(pv[1][2], pv[1][3]);
        t1.u4[0] = cvtpk(pv[2][0], pv[2][1]);
        t1.u4[1] = cvtpk(pv[2][2], pv[2][3]);
        t1.u4[2] = cvtpk(pv[3][0], pv[3][1]);
        t1.u4[3] = cvtpk(pv[3][2], pv[3][3]);
        ap[g][0] = t0.v;
        ap[g][1] = t1.v;
      }

      // O += P.V
#pragma unroll
      for (int hh = 0; hh < 2; ++hh)
#pragma unroll
        for (int di = 0; di < 4; ++di) {
          bf16x8 bv = VC[hh][di];
#pragma unroll
          for (int g = 0; g < 2; ++g)
            accO[g][di] = MFMA16(ap[g][hh], bv, accO[g][di], 0, 0, 0);
        }
      // l += P.1 (MFMA does the cross-quad k-reduction)
#pragma unroll
      for (int g = 0; g < 2; ++g) {
        accL[g] = MFMA16(ap[g][0], onesf, accL[g], 0, 0, 0);
        accL[g] = MFMA16(ap[g][1], onesf, accL[g], 0, 0, 0);
      }
    };

    for (int kt = par; kt <= ktmax; ) {
      tile(kt, kA, kB, vA, vB); kt += 2;
      if (kt > ktmax) break;
      tile(kt, kB, kA, vB, vA); kt += 2;
    }

    // ---- exact parity combine (per-lane values) ----
    if (par) {
      float* cb = CB[lane];
#pragma unroll
      for (int g = 0; g < 2; ++g) {
#pragma unroll
        for (int di = 0; di < 4; ++di)
#pragma unroll
          for (int r = 0; r < 4; ++r)
            cb[g * 16 + di * 4 + r] = accO[g][di][r];
#pragma unroll
        for (int r = 0; r < 4; ++r)
          cb[32 + g * 4 + r] = accL[g][r];
      }
    }
    __syncthreads();
    if (!par) {
      const float* cb = CB[lane];
#pragma unroll
      for (int g = 0; g < 2; ++g) {
#pragma unroll
        for (int di = 0; di < 4; ++di)
#pragma unroll
          for (int r = 0; r < 4; ++r)
            accO[g][di][r] += cb[g * 16 + di * 4 + r];
#pragma unroll
        for (int r = 0; r < 4; ++r)
          accL[g][r] += cb[32 + g * 4 + r];
      }
#pragma unroll
      for (int g = 0; g < 2; ++g)
#pragma unroll
        for (int r = 0; r < 4; ++r) {
          const float inv = 1.f / accL[g][r]; // lane holds l for its own rows
          const int q = q0 + g * 16 + quad * 4 + r;
          u16* op = outb + (size_t)q * 1024;
#pragma unroll
          for (int di = 0; di < 4; ++di)
            op[di * 16] = f2bf(accO[g][di][r] * inv);
        }
    }
    __syncthreads();   // CB safe for reuse by the next group
  };

  run_group(63 - u);   // heavy half
  run_group(u);        // light half -> every wave totals 16-17 tiles
}

// ---------------------------------------------------------------------------
extern "C" void kernel_launch(void* const* d_in, const int* in_sizes, int n_in,
                              void* d_out, int out_size, void* d_ws, size_t ws_size,
                              hipStream_t stream) {
  const float* x     = (const float*)d_in[0];
  const float* Wqkv  = (const float*)d_in[1];
  const float* bqkv  = (const float*)d_in[2];
  const float* Wproj = (const float*)d_in[3];
  const float* bproj = (const float*)d_in[4];
  float* out = (float*)d_out;

  char* ws = (char*)d_ws;
  u16* xb     = (u16*)(ws);                 //  8 MB  x bf16 [4096,1024]
  u16* wqkvT  = (u16*)(ws + 8388608);       //  6 MB  Wqkv^T bf16 [3072,1024]
  u16* wprojT = (u16*)(ws + 14680064);      //  2 MB  Wproj^T bf16 [1024,1024]
  u16* qb     = (u16*)(ws + 16777216);      //  8 MB  Q bf16 [4096,1024] (pre-scaled)
  u16* KF     = (u16*)(ws + 25165824);      //  8 MB  K fragment-order
  u16* VF     = (u16*)(ws + 33554432);      //  8 MB  V fragment-order (k-perm)
  u16* att    = (u16*)(ws + 41943040);      //  8 MB  attn out bf16 [4096,1024]

  constexpr float cs = 0.18033688011f;      // log2(e)/8

  prep<<<5120, 256, 0, stream>>>(x, xb, Wqkv, wqkvT, Wproj, wprojT);

  gemm_qkv<<<dim3(512), 256, 0, stream>>>(xb, wqkvT, bqkv, qb, KF, VF, cs);

  attn_bal<<<dim3(1024), 128, 0, stream>>>(qb, KF, VF, att);

  gemm_proj<<<dim3(512), 256, 0, stream>>>(att, wprojT, bproj, out);
}

// Round 9
// 152.346 us; speedup vs baseline: 1.0154x; 1.0154x over previous
//
#include <hip/hip_runtime.h>
#include <hip/hip_bf16.h>
#include <cstdint>

// ---------------------------------------------------------------------------
// CausalSelfAttention: x@Wqkv+b -> heads -> causal flash attn -> @Wproj+b
// B=2 T=2048 C=1024 H=16 Dh=64.
// R19: REVERT to R17 (149.6us best-known) + ONE isolated change:
//  prep W-transpose vectorized IN PLACE (same 8192 grid, same 32x32 tiles,
//  uniform block sizes): float4 loads (16B/lane, was 4B scalar), uint2
//  stores of 4 packed bf16 (8B/lane, was 2B scalar). Bit-identical f2bf.
//  - R18 post-mortem: 3 simultaneous changes while counter-blind -> +5.1us,
//    unattributable. Prime suspect: prep restructure created 1024 4x-heavy
//    tail blocks after 4096 light ones (R13 lesson re-imported). Reverted
//    qkv-2x2 and VF-pack too; neither retried without counters.
// R17 (kept): 2 independently-phased blocks/CU both GEMMs (m114 overlap);
//  1-phase body, counted vmcnt, granule XOR-swizzle (conflicts 0).
//  gemm_qkv: BM=128 BN=192, 4 waves @ 128x48, LDS 80KB, grid 512.
//  gemm_proj: BM=128 BN=64, 4 waves @ 64x32, LDS 48KB, grid 512.
// R14 (kept): attn uniform-wave (63-u then u), K+V depth-2 ping-pong,
//  l via ones-MFMA, cvt_pk pack.
// HARD-WON NOTES:
//  - R7: forcing low VGPR -> catastrophic spills.
//  - R13: VGPR>128 cliff; occupancy-DECAY from non-uniform block lengths
//    dominates per-tile thinning (applies to prep tiles too -- R18).
//  - R11: partial-coverage grids idle CUs; coverage before tile size.
//  - R15/R16: schedule tuning inside ONE barrier-locked block is futile;
//    independent co-resident blocks overlap mem and MFMA phases.
//  - R18: never bundle changes while counters are blinded.
// ---------------------------------------------------------------------------

using u16 = unsigned short;
using u32 = unsigned int;

typedef __bf16 bf16x8 __attribute__((ext_vector_type(8)));
typedef float f32x4 __attribute__((ext_vector_type(4)));

#define AS1 __attribute__((address_space(1)))
#define AS3 __attribute__((address_space(3)))

__device__ __forceinline__ u16 f2bf(float f) {
  u32 u = __float_as_uint(f);
  u += 0x7fffu + ((u >> 16) & 1u);   // RTNE
  return (u16)(u >> 16);
}
__device__ __forceinline__ u32 cvtpk(float a, float b) {
  u32 r;
  asm("v_cvt_pk_bf16_f32 %0, %1, %2" : "=v"(r) : "v"(a), "v"(b));
  return r;
}

// ---------------- prep: cvt x->bf16 (blocks 0..4095) + W transposes ---------
// W-transpose blocks (4096..8191): 32x32 f32 tile; float4 loads, LDS
// transpose (33-stride, <=2-way bank aliasing both sides), uint2 stores
// (4 packed bf16, bit-identical f2bf).
__global__ __launch_bounds__(256) void prep(const float* __restrict__ x,
                                            u16* __restrict__ xb,
                                            const float* __restrict__ W0,
                                            u16* __restrict__ T0,
                                            const float* __restrict__ W1,
                                            u16* __restrict__ T1) {
  const int bx = blockIdx.x;
  const int tid = threadIdx.x;
  if (bx < 4096) {
    const int i = bx * 256 + tid;
    float4 v = ((const float4*)x)[i];
    ushort4 o;
    o.x = f2bf(v.x); o.y = f2bf(v.y); o.z = f2bf(v.z); o.w = f2bf(v.w);
    ((ushort4*)xb)[i] = o;
    return;
  }
  __shared__ float t[32][33];
  const int idx = bx - 4096;          // 128 n-tiles x 32 k-tiles
  const int bxx = idx & 127, by = idx >> 7;
  const float* W; u16* Wt; int N, n0;
  if (bxx < 96) { W = W0; Wt = T0; N = 3072; n0 = bxx * 32; }
  else          { W = W1; Wt = T1; N = 1024; n0 = (bxx - 96) * 32; }
  const int k0 = by * 32;

  // load: one float4 per thread (k-row = tid>>3, n-cols (tid&7)*4 ..+3)
  const int lr = tid >> 3, lc = (tid & 7) * 4;
  const float4 v = *(const float4*)&W[(size_t)(k0 + lr) * N + n0 + lc];
  t[lr][lc + 0] = v.x;
  t[lr][lc + 1] = v.y;
  t[lr][lc + 2] = v.z;
  t[lr][lc + 3] = v.w;
  __syncthreads();
  // store: one uint2 (4 bf16) per thread (n-row = tid>>3, k-cols (tid&7)*4)
  const int nr = tid >> 3, kc = (tid & 7) * 4;
  const u16 b0 = f2bf(t[kc + 0][nr]);
  const u16 b1 = f2bf(t[kc + 1][nr]);
  const u16 b2 = f2bf(t[kc + 2][nr]);
  const u16 b3 = f2bf(t[kc + 3][nr]);
  uint2 o;
  o.x = (u32)b0 | ((u32)b1 << 16);
  o.y = (u32)b2 | ((u32)b3 << 16);
  *(uint2*)&Wt[(size_t)(n0 + nr) * 1024 + k0 + kc] = o;
}

// ---------------- QKV GEMM: 128x192, 2 blocks/CU, 1-phase -------------------
// n<1024: Q (scaled by cs) -> qb[4096][1024]
// 1024<=n<2048: K -> KF fragment order [bh][kt][m][hh][lane][8]
// n>=2048:     V -> VF fragment order [bh][kt][hh][di][lane][8] (k-permuted)
#define MFMA16 __builtin_amdgcn_mfma_f32_16x16x32_bf16

__global__ __launch_bounds__(256, 2) void gemm_qkv(const u16* __restrict__ A,
                                                   const u16* __restrict__ Bt,
                                                   const float* __restrict__ bias,
                                                   u16* __restrict__ qb,
                                                   u16* __restrict__ KF,
                                                   u16* __restrict__ VF,
                                                   float sc_val) {
  constexpr int NT = 16;                    // K=1024 / BK=64
  constexpr int BUFO = 5 * 4096;            // u16 per buffer (A0,A1,B0,B1,B2)
  __shared__ __align__(16) u16 sm[2 * BUFO];  // 80 KiB -> 2 blocks/CU

  const int tid  = threadIdx.x;
  const int lane = tid & 63;
  const int w    = tid >> 6;          // 0..3
  const int quad = lane >> 4;
  const int l15  = lane & 15;

  // block -> tile: 512 blocks = 8 XCD x 64; each XCD: 4 mt x 16 nt
  const int bid = blockIdx.x;
  const int xcd = bid & 7, c = bid >> 3;     // c 0..63
  const int mt = xcd * 4 + (c & 3);          // 0..31
  const int nt = c >> 2;                     // 0..15
  const int bm = mt * 128, bn = nt * 192;

  const int wc = w * 48;              // wave cols; all waves share rows 0..127

  // ---- staging: thread writes 16B linearly at chunk + tid*16 (2 halves).
  const int srow = tid >> 3;          // 0..31
  const int scol = (((tid & 7) ^ ((tid >> 3) & 7)) << 3);

#define STAGEA(ch, ktile, bufo)                                                 \
  do {                                                                          \
    const u16* _s = A + (size_t)(bm + (ch) * 64 + srow) * 1024 +                \
                    ((ktile) << 6) + scol;                                      \
    u16* _d = sm + (bufo) + (ch) * 4096 + tid * 8;                              \
    __builtin_amdgcn_global_load_lds((AS1 const void*)_s, (AS3 void*)_d,        \
                                     16, 0, 0);                                 \
    __builtin_amdgcn_global_load_lds((AS1 const void*)(_s + (32 << 10)),        \
                                     (AS3 void*)(_d + 2048), 16, 0, 0);         \
  } while (0)
#define STAGEB(ch, ktile, bufo)                                                 \
  do {                                                                          \
    const u16* _s = Bt + (size_t)(bn + (ch) * 64 + srow) * 1024 +               \
                    ((ktile) << 6) + scol;                                      \
    u16* _d = sm + (bufo) + (2 + (ch)) * 4096 + tid * 8;                        \
    __builtin_amdgcn_global_load_lds((AS1 const void*)_s, (AS3 void*)_d,        \
                                     16, 0, 0);                                 \
    __builtin_amdgcn_global_load_lds((AS1 const void*)(_s + (32 << 10)),        \
                                     (AS3 void*)(_d + 2048), 16, 0, 0);         \
  } while (0)

  // ---- ds-read bases (swizzled granule; row&7 == l15&7 everywhere)
  int abase_lo[4], abase_hi[4], bbase[3];
#pragma unroll
  for (int mi = 0; mi < 4; ++mi) {
    abase_lo[mi] = 0 * 4096 + (mi * 16 + l15) * 64;     // rows 0..63
    abase_hi[mi] = 1 * 4096 + (mi * 16 + l15) * 64;     // rows 64..127
  }
#pragma unroll
  for (int ni = 0; ni < 3; ++ni) {
    const int rb = wc + ni * 16 + l15;                  // 0..191
    bbase[ni] = (2 + (rb >> 6)) * 4096 + (rb & 63) * 64;
  }
  const int sw0 = ((quad ^ (l15 & 7)) << 3);
  const int sw1 = sw0 ^ 32;

  // ---- prologue: kt0 all 5 -> buf0 (10 issues); A01(kt1) -> buf1 (4)
  STAGEA(0, 0, 0); STAGEA(1, 0, 0);
  STAGEB(0, 0, 0); STAGEB(1, 0, 0); STAGEB(2, 0, 0);
  STAGEA(0, 1, BUFO); STAGEA(1, 1, BUFO);
  asm volatile("s_waitcnt vmcnt(4)" ::: "memory");  // kt0's 10 landed
  __builtin_amdgcn_s_barrier();

  f32x4 acc[8][3] = {};
  bf16x8 alo[4][2], ahi[4][2], b[3][2];

#pragma unroll 2
  for (int j = 0; j < NT; ++j) {
    const int bo  = (j & 1) * BUFO;
    const int nbo = bo ^ BUFO;
    const u16* smb = sm + bo;

    // ---- issue ALL 22 ds_reads (buf j fully landed at this point) ----
#pragma unroll
    for (int mi = 0; mi < 4; ++mi) {
      alo[mi][0] = *(const bf16x8*)(smb + abase_lo[mi] + sw0);
      alo[mi][1] = *(const bf16x8*)(smb + abase_lo[mi] + sw1);
    }
#pragma unroll
    for (int ni = 0; ni < 2; ++ni) {
      b[ni][0] = *(const bf16x8*)(smb + bbase[ni] + sw0);
      b[ni][1] = *(const bf16x8*)(smb + bbase[ni] + sw1);
    }
#pragma unroll
    for (int mi = 0; mi < 4; ++mi) {
      ahi[mi][0] = *(const bf16x8*)(smb + abase_hi[mi] + sw0);
      ahi[mi][1] = *(const bf16x8*)(smb + abase_hi[mi] + sw1);
    }
    b[2][0] = *(const bf16x8*)(smb + bbase[2] + sw0);
    b[2][1] = *(const bf16x8*)(smb + bbase[2] + sw1);
    // stage B(j+1) -> other buffer (its B chunks drained in tile j-1)
    if (j + 1 < NT) { STAGEB(0, j + 1, nbo); STAGEB(1, j + 1, nbo); STAGEB(2, j + 1, nbo); }

    asm volatile("s_waitcnt lgkmcnt(10)" ::: "memory");  // alo+b01 (12) landed
    __builtin_amdgcn_sched_barrier(0);
    __builtin_amdgcn_s_setprio(1);
    // MFMA grp0: alo x b01 (reads 13-22 complete underneath)
#pragma unroll
    for (int mi = 0; mi < 4; ++mi)
#pragma unroll
      for (int ni = 0; ni < 2; ++ni) {
        acc[mi][ni] = MFMA16(alo[mi][0], b[ni][0], acc[mi][ni], 0, 0, 0);
        acc[mi][ni] = MFMA16(alo[mi][1], b[ni][1], acc[mi][ni], 0, 0, 0);
      }
    __builtin_amdgcn_s_setprio(0);
    asm volatile("s_waitcnt lgkmcnt(0)" ::: "memory");   // all 22 landed
    __builtin_amdgcn_sched_barrier(0);
    __builtin_amdgcn_s_barrier();     // every wave done READING buf j
    // stage A(j+2) -> CURRENT buffer (safe: reads retired to registers)
    if (j + 2 < NT) { STAGEA(0, j + 2, bo); STAGEA(1, j + 2, bo); }
    __builtin_amdgcn_s_setprio(1);
    // MFMA grp1 (register-only; runs over the staging writes)
#pragma unroll
    for (int mi = 0; mi < 4; ++mi) {
      acc[mi][2] = MFMA16(alo[mi][0], b[2][0], acc[mi][2], 0, 0, 0);
      acc[mi][2] = MFMA16(alo[mi][1], b[2][1], acc[mi][2], 0, 0, 0);
      acc[4 + mi][0] = MFMA16(ahi[mi][0], b[0][0], acc[4 + mi][0], 0, 0, 0);
      acc[4 + mi][0] = MFMA16(ahi[mi][1], b[0][1], acc[4 + mi][0], 0, 0, 0);
    }
#pragma unroll
    for (int mi = 0; mi < 4; ++mi)
#pragma unroll
      for (int ni = 1; ni < 3; ++ni) {
        acc[4 + mi][ni] = MFMA16(ahi[mi][0], b[ni][0], acc[4 + mi][ni], 0, 0, 0);
        acc[4 + mi][ni] = MFMA16(ahi[mi][1], b[ni][1], acc[4 + mi][ni], 0, 0, 0);
      }
    __builtin_amdgcn_s_setprio(0);
    if (j + 2 < NT)
      asm volatile("s_waitcnt vmcnt(4)" ::: "memory"); // A(j+1)+B(j+1) landed
    else
      asm volatile("s_waitcnt vmcnt(0)" ::: "memory"); // tail drain
    __builtin_amdgcn_s_barrier();
  }
#undef STAGEA
#undef STAGEB

  // ---- epilogue: per-ni region branch (192-wide blocks straddle Q/K/V) ----
  const int crow0 = bm + (quad << 2);
  const int ccol0 = bn + wc + l15;
#pragma unroll
  for (int ni = 0; ni < 3; ++ni) {
    const int n = ccol0 + ni * 16;
    const float bv = bias[n];
    if (n < 1024) {                     // ---- Q (scaled) ----
#pragma unroll
      for (int mi = 0; mi < 8; ++mi) {
        const int m0 = crow0 + mi * 16;
#pragma unroll
        for (int r = 0; r < 4; ++r)
          qb[(size_t)(m0 + r) * 1024 + n] = f2bf((acc[mi][ni][r] + bv) * sc_val);
      }
    } else if (n < 2048) {              // ---- K fragment order ----
      const int hk = (n - 1024) >> 6;
      const int d  = (n - 1024) & 63;
      const int hh = d >> 5, qd = (d >> 3) & 3, jj = d & 7;
#pragma unroll
      for (int mi = 0; mi < 8; ++mi) {
#pragma unroll
        for (int r = 0; r < 4; ++r) {
          const int t  = crow0 + mi * 16 + r;
          const int bb = t >> 11, tt = t & 2047;
          const int kt = tt >> 6, mm = (tt >> 4) & 3, l = tt & 15;
          KF[((size_t)((bb * 16 + hk) * 32 + kt) * 8 + mm * 2 + hh) * 512 +
             (qd * 16 + l) * 8 + jj] = f2bf(acc[mi][ni][r] + bv);
        }
      }
    } else {                            // ---- V fragment order (k-perm) ----
      const int hv = (n - 2048) >> 6;
      const int d  = (n - 2048) & 63;
      const int di = d >> 4, l = d & 15;
#pragma unroll
      for (int mi = 0; mi < 8; ++mi) {
#pragma unroll
        for (int r = 0; r < 4; ++r) {
          const int t  = crow0 + mi * 16 + r;
          const int bb = t >> 11, tt = t & 2047;
          const int kt = tt >> 6, to = tt & 63;
          const int mq = to >> 4, qd2 = (to >> 2) & 3, rr = to & 3;
          const int hh = mq >> 1, jj = (mq & 1) * 4 + rr;
          VF[((size_t)((bb * 16 + hv) * 32 + kt) * 8 + hh * 4 + di) * 512 +
             (qd2 * 16 + l) * 8 + jj] = f2bf(acc[mi][ni][r] + bv);
        }
      }
    }
  }
}

// ---------------- Proj GEMM: 128x64, 2 blocks/CU, 1-phase -------------------
// M=4096 N=1024 K=1024, fp32 out.  512 blocks (32 mt x 16 nt), 256 thr,
// 4 waves @ 64x32 (acc[4][2]).  LDS 2 bufs x {A0,A1,B0} = 48 KiB.
__global__ __launch_bounds__(256, 2) void gemm_proj(const u16* __restrict__ A,
                                                    const u16* __restrict__ Bt,
                                                    const float* __restrict__ bias,
                                                    float* __restrict__ C) {
  constexpr int NT = 16;                    // K=1024 / BK=64
  constexpr int BUFO = 3 * 4096;            // u16 per buffer (A0,A1,B0)
  __shared__ __align__(16) u16 sm[2 * BUFO];  // 48 KiB

  const int tid  = threadIdx.x;
  const int lane = tid & 63;
  const int w    = tid >> 6;          // 0..3
  const int quad = lane >> 4;
  const int l15  = lane & 15;

  // 512 blocks = 8 XCD x 64: each XCD 4 mt x 16 nt
  const int bid = blockIdx.x;
  const int xcd = bid & 7, c = bid >> 3;     // c 0..63
  const int mt = xcd * 4 + (c & 3);          // 0..31
  const int nt = c >> 2;                     // 0..15
  const int bm = mt * 128, bn = nt * 64;

  const int wr = (w >> 1) * 64;       // wave rows (0/64)
  const int wcC = (w & 1) * 32;       // wave cols (0/32)

  const int srow = tid >> 3;
  const int scol = (((tid & 7) ^ ((tid >> 3) & 7)) << 3);

#define PSTAGEA(ch, ktile, bufo)                                                \
  do {                                                                          \
    const u16* _s = A + (size_t)(bm + (ch) * 64 + srow) * 1024 +                \
                    ((ktile) << 6) + scol;                                      \
    u16* _d = sm + (bufo) + (ch) * 4096 + tid * 8;                              \
    __builtin_amdgcn_global_load_lds((AS1 const void*)_s, (AS3 void*)_d,        \
                                     16, 0, 0);                                 \
    __builtin_amdgcn_global_load_lds((AS1 const void*)(_s + (32 << 10)),        \
                                     (AS3 void*)(_d + 2048), 16, 0, 0);         \
  } while (0)
#define PSTAGEB(ktile, bufo)                                                    \
  do {                                                                          \
    const u16* _s = Bt + (size_t)(bn + srow) * 1024 + ((ktile) << 6) + scol;    \
    u16* _d = sm + (bufo) + 2 * 4096 + tid * 8;                                 \
    __builtin_amdgcn_global_load_lds((AS1 const void*)_s, (AS3 void*)_d,        \
                                     16, 0, 0);                                 \
    __builtin_amdgcn_global_load_lds((AS1 const void*)(_s + (32 << 10)),        \
                                     (AS3 void*)(_d + 2048), 16, 0, 0);         \
  } while (0)

  int abase[4], bbase[2];
#pragma unroll
  for (int mi = 0; mi < 4; ++mi)
    abase[mi] = (w >> 1) * 4096 + (mi * 16 + l15) * 64;
#pragma unroll
  for (int ni = 0; ni < 2; ++ni)
    bbase[ni] = 2 * 4096 + (wcC + ni * 16 + l15) * 64;
  const int sw0 = ((quad ^ (l15 & 7)) << 3);
  const int sw1 = sw0 ^ 32;

  // prologue: kt0 {A0,A1,B0} -> buf0 (6); A01(kt1) -> buf1 (4)
  PSTAGEA(0, 0, 0); PSTAGEA(1, 0, 0); PSTAGEB(0, 0);
  PSTAGEA(0, 1, BUFO); PSTAGEA(1, 1, BUFO);
  asm volatile("s_waitcnt vmcnt(4)" ::: "memory");  // kt0's 6 landed
  __builtin_amdgcn_s_barrier();

  f32x4 acc[4][2] = {};
  bf16x8 a[4][2], b[2][2];

#pragma unroll 2
  for (int j = 0; j < NT; ++j) {
    const int bo  = (j & 1) * BUFO;
    const int nbo = bo ^ BUFO;
    const u16* smb = sm + bo;

    // ---- issue ALL 12 ds_reads; stage B(j+1)->other ----
#pragma unroll
    for (int mi = 0; mi < 4; ++mi) {
      a[mi][0] = *(const bf16x8*)(smb + abase[mi] + sw0);
      a[mi][1] = *(const bf16x8*)(smb + abase[mi] + sw1);
    }
#pragma unroll
    for (int ni = 0; ni < 2; ++ni) {
      b[ni][0] = *(const bf16x8*)(smb + bbase[ni] + sw0);
      b[ni][1] = *(const bf16x8*)(smb + bbase[ni] + sw1);
    }
    if (j + 1 < NT) PSTAGEB(j + 1, nbo);

    asm volatile("s_waitcnt lgkmcnt(2)" ::: "memory");   // a + b0 landed
    __builtin_amdgcn_sched_barrier(0);
    __builtin_amdgcn_s_setprio(1);
#pragma unroll
    for (int mi = 0; mi < 4; ++mi) {
      acc[mi][0] = MFMA16(a[mi][0], b[0][0], acc[mi][0], 0, 0, 0);
      acc[mi][0] = MFMA16(a[mi][1], b[0][1], acc[mi][0], 0, 0, 0);
    }
    __builtin_amdgcn_s_setprio(0);
    asm volatile("s_waitcnt lgkmcnt(0)" ::: "memory");   // all 12 landed
    __builtin_amdgcn_sched_barrier(0);
    __builtin_amdgcn_s_barrier();     // every wave done READING buf j
    if (j + 2 < NT) { PSTAGEA(0, j + 2, bo); PSTAGEA(1, j + 2, bo); }
    __builtin_amdgcn_s_setprio(1);
#pragma unroll
    for (int mi = 0; mi < 4; ++mi) {
      acc[mi][1] = MFMA16(a[mi][0], b[1][0], acc[mi][1], 0, 0, 0);
      acc[mi][1] = MFMA16(a[mi][1], b[1][1], acc[mi][1], 0, 0, 0);
    }
    __builtin_amdgcn_s_setprio(0);
    if (j + 2 < NT)
      asm volatile("s_waitcnt vmcnt(4)" ::: "memory"); // A(j+1)+B(j+1) landed
    else
      asm volatile("s_waitcnt vmcnt(0)" ::: "memory"); // tail drain
    __builtin_amdgcn_s_barrier();
  }
#undef PSTAGEA
#undef PSTAGEB

  const int crow0 = bm + wr + (quad << 2);
  const int ccol0 = bn + wcC + l15;
#pragma unroll
  for (int ni = 0; ni < 2; ++ni) {
    const int n = ccol0 + ni * 16;
    const float bv = bias[n];
#pragma unroll
    for (int mi = 0; mi < 4; ++mi) {
      const int m0 = crow0 + mi * 16;
#pragma unroll
      for (int r = 0; r < 4; ++r)
        C[(size_t)(m0 + r) * 1024 + n] = acc[mi][ni][r] + bv;
    }
  }
}

// ---------------- uniform-wave pipelined MFMA flash attention ---------------
// grid 1024 x 128 threads.  bid: xcd = bid&7 (4 bh per XCD, KV L2-resident);
// c = bid>>3: u = c&31 (q-group pair), bh = xcd | ((c>>5)<<3).
// Each wave: q-group 63-u fully, then q-group u (accO reused between groups).
// Parity waves split kt; per-wave total = 16-17 tiles UNIFORMLY across the
// whole grid -> 2 waves/SIMD resident for the entire kernel, no decay.
// K AND V prefetched depth-2 (kA/kB, vA/vB static ping-pong).
__global__ __launch_bounds__(128, 2) void attn_bal(const u16* __restrict__ qb,
                                                   const u16* __restrict__ KF,
                                                   const u16* __restrict__ VF,
                                                   u16* __restrict__ out) {
  const int bid = blockIdx.x;
  const int c   = bid >> 3;
  const int u   = c & 31;
  const int bh  = (bid & 7) | ((c >> 5) << 3);
  const int b = bh >> 4, h = bh & 15;
  const int tid = threadIdx.x;
  const int lane = tid & 63;
  const int par  = tid >> 6;          // wave 0/1 = kt parity
  const int quad = lane >> 4;
  const int l15  = lane & 15;

  __shared__ float CB[64][41];        // [lane][32 accO + 8 accL], stride 41

  const u16* qbase = qb + (size_t)b * 2048 * 1024 + h * 64;
  const size_t fb = (size_t)bh * 32 * 4096 + lane * 8;
  const u16* kfb = KF + fb;
  const u16* vfb = VF + fb;

  union { u32 u4[4]; bf16x8 v; } onesu;
  onesu.u4[0] = onesu.u4[1] = onesu.u4[2] = onesu.u4[3] = 0x3f803f80u;
  const bf16x8 onesf = onesu.v;       // bf16 1.0 x8

  u16* const outb = out + (size_t)b * 2048 * 1024 + h * 64 + l15;

  auto run_group = [&](int g32) {
    const int q0 = g32 * 32;
    const int ktmax = g32 >> 1;

    // Q B-frags for this group
    bf16x8 qf[2][2];
#pragma unroll
    for (int g = 0; g < 2; ++g)
#pragma unroll
      for (int hh = 0; hh < 2; ++hh)
        qf[g][hh] = *(const bf16x8*)(qbase + (size_t)(q0 + g * 16 + l15) * 1024 +
                                     hh * 32 + quad * 8);

    f32x4 accO[2][4] = {};            // [g][di]: q=quad*4+r, d=di*16+l15
    f32x4 accL[2] = {};               // [g]: l for q=quad*4+r

    // depth-2 K+V pipeline, two register sets (static ping-pong, no rotate)
    bf16x8 kA[4][2], kB[4][2], vA[2][4], vB[2][4];
    {
      const u16* kp = kfb + (size_t)par * 4096;
      const u16* vp = vfb + (size_t)par * 4096;
#pragma unroll
      for (int m = 0; m < 4; ++m)
#pragma unroll
        for (int hh = 0; hh < 2; ++hh)
          kA[m][hh] = *(const bf16x8*)(kp + (m * 2 + hh) * 512);
#pragma unroll
      for (int hh = 0; hh < 2; ++hh)
#pragma unroll
        for (int di = 0; di < 4; ++di)
          vA[hh][di] = *(const bf16x8*)(vp + (hh * 4 + di) * 512);
    }

    auto tile = [&](int kt, bf16x8 (&KC)[4][2], bf16x8 (&KN)[4][2],
                    bf16x8 (&VC)[2][4], bf16x8 (&VN)[2][4]) {
      // prefetch kt+2 (clamped) into the other register set
      const int ktn = (kt + 2 <= ktmax) ? kt + 2 : ktmax;
      const u16* kpn = kfb + (size_t)ktn * 4096;
      const u16* vpn = vfb + (size_t)ktn * 4096;
#pragma unroll
      for (int m = 0; m < 4; ++m)
#pragma unroll
        for (int hh = 0; hh < 2; ++hh)
          KN[m][hh] = *(const bf16x8*)(kpn + (m * 2 + hh) * 512);
#pragma unroll
      for (int hh = 0; hh < 2; ++hh)
#pragma unroll
        for (int di = 0; di < 4; ++di)
          VN[hh][di] = *(const bf16x8*)(vpn + (hh * 4 + di) * 512);

      const bool diag = (kt == ktmax);
      bf16x8 ap[2][2];
#pragma unroll
      for (int g = 0; g < 2; ++g) {
        f32x4 sT[4] = {};
#pragma unroll
        for (int m = 0; m < 4; ++m) {
          sT[m] = MFMA16(KC[m][0], qf[g][0], sT[m], 0, 0, 0);
          sT[m] = MFMA16(KC[m][1], qf[g][1], sT[m], 0, 0, 0);
        }
        float pv[4][4];
        if (diag) {                    // only the last tile pays mask ops
          const int qgl = q0 + g * 16 + l15;
#pragma unroll
          for (int m = 0; m < 4; ++m)
#pragma unroll
            for (int r = 0; r < 4; ++r) {
              const bool msk = (kt * 64 + m * 16 + quad * 4 + r) > qgl;
              pv[m][r] = msk ? 0.f : __builtin_amdgcn_exp2f(sT[m][r]);
            }
        } else {
#pragma unroll
          for (int m = 0; m < 4; ++m)
#pragma unroll
            for (int r = 0; r < 4; ++r)
              pv[m][r] = __builtin_amdgcn_exp2f(sT[m][r]);
        }
        union { u32 u4[4]; bf16x8 v; } t0, t1;
        t0.u4[0] = cvtpk(pv[0][0], pv[0][1]);
        t0.u4[1] = cvtpk(pv[0][2], pv[0][3]);
        t0.u4[2] = cvtpk(pv[1][0], pv[1][1]);
        t0.u4[3] = cvtpk(pv[1][2], pv[1][3]);
        t1.u4[0] = cvtpk(pv[2][0], pv[2][1]);
        t1.u4[1] = cvtpk(pv[2][2], pv[2][3]);
        t1.u4[2] = cvtpk(pv[3][0], pv[3][1]);
        t1.u4[3] = cvtpk(pv[3][2], pv[3][3]);
        ap[g][0] = t0.v;
        ap[g][1] = t1.v;
      }

      // O += P.V
#pragma unroll
      for (int hh = 0; hh < 2; ++hh)
#pragma unroll
        for (int di = 0; di < 4; ++di) {
          bf16x8 bv = VC[hh][di];
#pragma unroll
          for (int g = 0; g < 2; ++g)
            accO[g][di] = MFMA16(ap[g][hh], bv, accO[g][di], 0, 0, 0);
        }
      // l += P.1 (MFMA does the cross-quad k-reduction)
#pragma unroll
      for (int g = 0; g < 2; ++g) {
        accL[g] = MFMA16(ap[g][0], onesf, accL[g], 0, 0, 0);
        accL[g] = MFMA16(ap[g][1], onesf, accL[g], 0, 0, 0);
      }
    };

    for (int kt = par; kt <= ktmax; ) {
      tile(kt, kA, kB, vA, vB); kt += 2;
      if (kt > ktmax) break;
      tile(kt, kB, kA, vB, vA); kt += 2;
    }

    // ---- exact parity combine (per-lane values) ----
    if (par) {
      float* cb = CB[lane];
#pragma unroll
      for (int g = 0; g < 2; ++g) {
#pragma unroll
        for (int di = 0; di < 4; ++di)
#pragma unroll
          for (int r = 0; r < 4; ++r)
            cb[g * 16 + di * 4 + r] = accO[g][di][r];
#pragma unroll
        for (int r = 0; r < 4; ++r)
          cb[32 + g * 4 + r] = accL[g][r];
      }
    }
    __syncthreads();
    if (!par) {
      const float* cb = CB[lane];
#pragma unroll
      for (int g = 0; g < 2; ++g) {
#pragma unroll
        for (int di = 0; di < 4; ++di)
#pragma unroll
          for (int r = 0; r < 4; ++r)
            accO[g][di][r] += cb[g * 16 + di * 4 + r];
#pragma unroll
        for (int r = 0; r < 4; ++r)
          accL[g][r] += cb[32 + g * 4 + r];
      }
#pragma unroll
      for (int g = 0; g < 2; ++g)
#pragma unroll
        for (int r = 0; r < 4; ++r) {
          const float inv = 1.f / accL[g][r]; // lane holds l for its own rows
          const int q = q0 + g * 16 + quad * 4 + r;
          u16* op = outb + (size_t)q * 1024;
#pragma unroll
          for (int di = 0; di < 4; ++di)
            op[di * 16] = f2bf(accO[g][di][r] * inv);
        }
    }
    __syncthreads();   // CB safe for reuse by the next group
  };

  run_group(63 - u);   // heavy half
  run_group(u);        // light half -> every wave totals 16-17 tiles
}

// ---------------------------------------------------------------------------
extern "C" void kernel_launch(void* const* d_in, const int* in_sizes, int n_in,
                              void* d_out, int out_size, void* d_ws, size_t ws_size,
                              hipStream_t stream) {
  const float* x     = (const float*)d_in[0];
  const float* Wqkv  = (const float*)d_in[1];
  const float* bqkv  = (const float*)d_in[2];
  const float* Wproj = (const float*)d_in[3];
  const float* bproj = (const float*)d_in[4];
  float* out = (float*)d_out;

  char* ws = (char*)d_ws;
  u16* xb     = (u16*)(ws);                 //  8 MB  x bf16 [4096,1024]
  u16* wqkvT  = (u16*)(ws + 8388608);       //  6 MB  Wqkv^T bf16 [3072,1024]
  u16* wprojT = (u16*)(ws + 14680064);      //  2 MB  Wproj^T bf16 [1024,1024]
  u16* qb     = (u16*)(ws + 16777216);      //  8 MB  Q bf16 [4096,1024] (pre-scaled)
  u16* KF     = (u16*)(ws + 25165824);      //  8 MB  K fragment-order
  u16* VF     = (u16*)(ws + 33554432);      //  8 MB  V fragment-order (k-perm)
  u16* att    = (u16*)(ws + 41943040);      //  8 MB  attn out bf16 [4096,1024]

  constexpr float cs = 0.18033688011f;      // log2(e)/8

  prep<<<8192, 256, 0, stream>>>(x, xb, Wqkv, wqkvT, Wproj, wprojT);

  gemm_qkv<<<dim3(512), 256, 0, stream>>>(xb, wqkvT, bqkv, qb, KF, VF, cs);

  attn_bal<<<dim3(1024), 128, 0, stream>>>(qb, KF, VF, att);

  gemm_proj<<<dim3(512), 256, 0, stream>>>(att, wprojT, bproj, out);
}

// Round 10
// 151.011 us; speedup vs baseline: 1.0244x; 1.0088x over previous
//
#include <hip/hip_runtime.h>
#include <hip/hip_bf16.h>
#include <cstdint>

// ---------------------------------------------------------------------------
// CausalSelfAttention: x@Wqkv+b -> heads -> causal flash attn -> @Wproj+b
// B=2 T=2048 C=1024 H=16 Dh=64.
// R20: re-anchor at R17 (149.6us best-known) + ONE isolated micro-change:
//  qkv VF epilogue packed stores. For fixed (mi,ni): t = crow0+mi*16+r with
//  crow0%4==0 -> to&15 = quad*4+r, so mq=to>>4 and qd2=(to>>2)&3=quad are
//  r-invariant and jj=(mq&1)*4+r is consecutive -> r=0..3 are 4 consecutive
//  u16. Pack via cvtpk (RTNE, bit-compatible with f2bf; already validated on
//  attn's P-path) -> one aligned uint2 store. V-region: 96 -> 24 stores/thr.
//  - R19 post-mortem: prep-vec predicted -3.5, delivered +2.7 (noise band
//    +-2.5). prep is already near its streaming floor; reverted to R17 prep.
// R17 (kept): 2 independently-phased blocks/CU both GEMMs (m114 overlap);
//  1-phase body, counted vmcnt, granule XOR-swizzle (conflicts 3.1M->0).
//  gemm_qkv: BM=128 BN=192, 4 waves @ 128x48, LDS 80KB, grid 512.
//  gemm_proj: BM=128 BN=64, 4 waves @ 64x32, LDS 48KB, grid 512.
// R14 (kept): attn uniform-wave (63-u then u), K+V depth-2 ping-pong,
//  l via ones-MFMA, cvt_pk pack. attn ~1075 TF effective (73% of HK-class).
// HARD-WON NOTES:
//  - R7: forcing low VGPR via launch_bounds -> catastrophic spills.
//  - R13: VGPR>128 cliff; occupancy-DECAY from non-uniform block lengths
//    dominates per-tile thinning (applies to prep tiles too -- R18).
//  - R11: partial-coverage grids idle CUs; coverage before tile size.
//  - R15/R16: schedule tuning inside ONE barrier-locked block is futile;
//    independent co-resident blocks overlap mem and MFMA phases.
//  - R18: never bundle changes while counters are blinded.
//  - R19: wall noise is +-2.5us; deltas below that are unverifiable here.
// ---------------------------------------------------------------------------

using u16 = unsigned short;
using u32 = unsigned int;

typedef __bf16 bf16x8 __attribute__((ext_vector_type(8)));
typedef float f32x4 __attribute__((ext_vector_type(4)));

#define AS1 __attribute__((address_space(1)))
#define AS3 __attribute__((address_space(3)))

__device__ __forceinline__ u16 f2bf(float f) {
  u32 u = __float_as_uint(f);
  u += 0x7fffu + ((u >> 16) & 1u);   // RTNE
  return (u16)(u >> 16);
}
__device__ __forceinline__ u32 cvtpk(float a, float b) {
  u32 r;
  asm("v_cvt_pk_bf16_f32 %0, %1, %2" : "=v"(r) : "v"(a), "v"(b));
  return r;
}

// ---------------- prep: cvt x->bf16 (blocks 0..4095) + W transposes ---------
__global__ __launch_bounds__(256) void prep(const float* __restrict__ x,
                                            u16* __restrict__ xb,
                                            const float* __restrict__ W0,
                                            u16* __restrict__ T0,
                                            const float* __restrict__ W1,
                                            u16* __restrict__ T1) {
  const int bx = blockIdx.x;
  const int tid = threadIdx.x;
  if (bx < 4096) {
    const int i = bx * 256 + tid;
    float4 v = ((const float4*)x)[i];
    ushort4 o;
    o.x = f2bf(v.x); o.y = f2bf(v.y); o.z = f2bf(v.z); o.w = f2bf(v.w);
    ((ushort4*)xb)[i] = o;
    return;
  }
  __shared__ float t[32][33];
  const int idx = bx - 4096;          // 128 n-tiles x 32 k-tiles
  const int bxx = idx & 127, by = idx >> 7;
  const float* W; u16* Wt; int N, n0;
  if (bxx < 96) { W = W0; Wt = T0; N = 3072; n0 = bxx * 32; }
  else          { W = W1; Wt = T1; N = 1024; n0 = (bxx - 96) * 32; }
  const int k0 = by * 32;
  const int tx = tid & 31, ty = tid >> 5;
#pragma unroll
  for (int i = 0; i < 4; ++i)
    t[ty + i * 8][tx] = W[(size_t)(k0 + ty + i * 8) * N + n0 + tx];
  __syncthreads();
#pragma unroll
  for (int i = 0; i < 4; ++i)
    Wt[(size_t)(n0 + ty + i * 8) * 1024 + k0 + tx] = f2bf(t[tx][ty + i * 8]);
}

// ---------------- QKV GEMM: 128x192, 2 blocks/CU, 1-phase -------------------
// n<1024: Q (scaled by cs) -> qb[4096][1024]
// 1024<=n<2048: K -> KF fragment order [bh][kt][m][hh][lane][8]
// n>=2048:     V -> VF fragment order [bh][kt][hh][di][lane][8] (k-permuted)
#define MFMA16 __builtin_amdgcn_mfma_f32_16x16x32_bf16

__global__ __launch_bounds__(256, 2) void gemm_qkv(const u16* __restrict__ A,
                                                   const u16* __restrict__ Bt,
                                                   const float* __restrict__ bias,
                                                   u16* __restrict__ qb,
                                                   u16* __restrict__ KF,
                                                   u16* __restrict__ VF,
                                                   float sc_val) {
  constexpr int NT = 16;                    // K=1024 / BK=64
  constexpr int BUFO = 5 * 4096;            // u16 per buffer (A0,A1,B0,B1,B2)
  __shared__ __align__(16) u16 sm[2 * BUFO];  // 80 KiB -> 2 blocks/CU

  const int tid  = threadIdx.x;
  const int lane = tid & 63;
  const int w    = tid >> 6;          // 0..3
  const int quad = lane >> 4;
  const int l15  = lane & 15;

  // block -> tile: 512 blocks = 8 XCD x 64; each XCD: 4 mt x 16 nt
  const int bid = blockIdx.x;
  const int xcd = bid & 7, c = bid >> 3;     // c 0..63
  const int mt = xcd * 4 + (c & 3);          // 0..31
  const int nt = c >> 2;                     // 0..15
  const int bm = mt * 128, bn = nt * 192;

  const int wc = w * 48;              // wave cols; all waves share rows 0..127

  // ---- staging: thread writes 16B linearly at chunk + tid*16 (2 halves).
  const int srow = tid >> 3;          // 0..31
  const int scol = (((tid & 7) ^ ((tid >> 3) & 7)) << 3);

#define STAGEA(ch, ktile, bufo)                                                 \
  do {                                                                          \
    const u16* _s = A + (size_t)(bm + (ch) * 64 + srow) * 1024 +                \
                    ((ktile) << 6) + scol;                                      \
    u16* _d = sm + (bufo) + (ch) * 4096 + tid * 8;                              \
    __builtin_amdgcn_global_load_lds((AS1 const void*)_s, (AS3 void*)_d,        \
                                     16, 0, 0);                                 \
    __builtin_amdgcn_global_load_lds((AS1 const void*)(_s + (32 << 10)),        \
                                     (AS3 void*)(_d + 2048), 16, 0, 0);         \
  } while (0)
#define STAGEB(ch, ktile, bufo)                                                 \
  do {                                                                          \
    const u16* _s = Bt + (size_t)(bn + (ch) * 64 + srow) * 1024 +               \
                    ((ktile) << 6) + scol;                                      \
    u16* _d = sm + (bufo) + (2 + (ch)) * 4096 + tid * 8;                        \
    __builtin_amdgcn_global_load_lds((AS1 const void*)_s, (AS3 void*)_d,        \
                                     16, 0, 0);                                 \
    __builtin_amdgcn_global_load_lds((AS1 const void*)(_s + (32 << 10)),        \
                                     (AS3 void*)(_d + 2048), 16, 0, 0);         \
  } while (0)

  // ---- ds-read bases (swizzled granule; row&7 == l15&7 everywhere)
  int abase_lo[4], abase_hi[4], bbase[3];
#pragma unroll
  for (int mi = 0; mi < 4; ++mi) {
    abase_lo[mi] = 0 * 4096 + (mi * 16 + l15) * 64;     // rows 0..63
    abase_hi[mi] = 1 * 4096 + (mi * 16 + l15) * 64;     // rows 64..127
  }
#pragma unroll
  for (int ni = 0; ni < 3; ++ni) {
    const int rb = wc + ni * 16 + l15;                  // 0..191
    bbase[ni] = (2 + (rb >> 6)) * 4096 + (rb & 63) * 64;
  }
  const int sw0 = ((quad ^ (l15 & 7)) << 3);
  const int sw1 = sw0 ^ 32;

  // ---- prologue: kt0 all 5 -> buf0 (10 issues); A01(kt1) -> buf1 (4)
  STAGEA(0, 0, 0); STAGEA(1, 0, 0);
  STAGEB(0, 0, 0); STAGEB(1, 0, 0); STAGEB(2, 0, 0);
  STAGEA(0, 1, BUFO); STAGEA(1, 1, BUFO);
  asm volatile("s_waitcnt vmcnt(4)" ::: "memory");  // kt0's 10 landed
  __builtin_amdgcn_s_barrier();

  f32x4 acc[8][3] = {};
  bf16x8 alo[4][2], ahi[4][2], b[3][2];

#pragma unroll 2
  for (int j = 0; j < NT; ++j) {
    const int bo  = (j & 1) * BUFO;
    const int nbo = bo ^ BUFO;
    const u16* smb = sm + bo;

    // ---- issue ALL 22 ds_reads (buf j fully landed at this point) ----
#pragma unroll
    for (int mi = 0; mi < 4; ++mi) {
      alo[mi][0] = *(const bf16x8*)(smb + abase_lo[mi] + sw0);
      alo[mi][1] = *(const bf16x8*)(smb + abase_lo[mi] + sw1);
    }
#pragma unroll
    for (int ni = 0; ni < 2; ++ni) {
      b[ni][0] = *(const bf16x8*)(smb + bbase[ni] + sw0);
      b[ni][1] = *(const bf16x8*)(smb + bbase[ni] + sw1);
    }
#pragma unroll
    for (int mi = 0; mi < 4; ++mi) {
      ahi[mi][0] = *(const bf16x8*)(smb + abase_hi[mi] + sw0);
      ahi[mi][1] = *(const bf16x8*)(smb + abase_hi[mi] + sw1);
    }
    b[2][0] = *(const bf16x8*)(smb + bbase[2] + sw0);
    b[2][1] = *(const bf16x8*)(smb + bbase[2] + sw1);
    // stage B(j+1) -> other buffer (its B chunks drained in tile j-1)
    if (j + 1 < NT) { STAGEB(0, j + 1, nbo); STAGEB(1, j + 1, nbo); STAGEB(2, j + 1, nbo); }

    asm volatile("s_waitcnt lgkmcnt(10)" ::: "memory");  // alo+b01 (12) landed
    __builtin_amdgcn_sched_barrier(0);
    __builtin_amdgcn_s_setprio(1);
    // MFMA grp0: alo x b01 (reads 13-22 complete underneath)
#pragma unroll
    for (int mi = 0; mi < 4; ++mi)
#pragma unroll
      for (int ni = 0; ni < 2; ++ni) {
        acc[mi][ni] = MFMA16(alo[mi][0], b[ni][0], acc[mi][ni], 0, 0, 0);
        acc[mi][ni] = MFMA16(alo[mi][1], b[ni][1], acc[mi][ni], 0, 0, 0);
      }
    __builtin_amdgcn_s_setprio(0);
    asm volatile("s_waitcnt lgkmcnt(0)" ::: "memory");   // all 22 landed
    __builtin_amdgcn_sched_barrier(0);
    __builtin_amdgcn_s_barrier();     // every wave done READING buf j
    // stage A(j+2) -> CURRENT buffer (safe: reads retired to registers)
    if (j + 2 < NT) { STAGEA(0, j + 2, bo); STAGEA(1, j + 2, bo); }
    __builtin_amdgcn_s_setprio(1);
    // MFMA grp1 (register-only; runs over the staging writes)
#pragma unroll
    for (int mi = 0; mi < 4; ++mi) {
      acc[mi][2] = MFMA16(alo[mi][0], b[2][0], acc[mi][2], 0, 0, 0);
      acc[mi][2] = MFMA16(alo[mi][1], b[2][1], acc[mi][2], 0, 0, 0);
      acc[4 + mi][0] = MFMA16(ahi[mi][0], b[0][0], acc[4 + mi][0], 0, 0, 0);
      acc[4 + mi][0] = MFMA16(ahi[mi][1], b[0][1], acc[4 + mi][0], 0, 0, 0);
    }
#pragma unroll
    for (int mi = 0; mi < 4; ++mi)
#pragma unroll
      for (int ni = 1; ni < 3; ++ni) {
        acc[4 + mi][ni] = MFMA16(ahi[mi][0], b[ni][0], acc[4 + mi][ni], 0, 0, 0);
        acc[4 + mi][ni] = MFMA16(ahi[mi][1], b[ni][1], acc[4 + mi][ni], 0, 0, 0);
      }
    __builtin_amdgcn_s_setprio(0);
    if (j + 2 < NT)
      asm volatile("s_waitcnt vmcnt(4)" ::: "memory"); // A(j+1)+B(j+1) landed
    else
      asm volatile("s_waitcnt vmcnt(0)" ::: "memory"); // tail drain
    __builtin_amdgcn_s_barrier();
  }
#undef STAGEA
#undef STAGEB

  // ---- epilogue: per-ni region branch (192-wide blocks straddle Q/K/V) ----
  const int crow0 = bm + (quad << 2);
  const int ccol0 = bn + wc + l15;
#pragma unroll
  for (int ni = 0; ni < 3; ++ni) {
    const int n = ccol0 + ni * 16;
    const float bv = bias[n];
    if (n < 1024) {                     // ---- Q (scaled) ----
#pragma unroll
      for (int mi = 0; mi < 8; ++mi) {
        const int m0 = crow0 + mi * 16;
#pragma unroll
        for (int r = 0; r < 4; ++r)
          qb[(size_t)(m0 + r) * 1024 + n] = f2bf((acc[mi][ni][r] + bv) * sc_val);
      }
    } else if (n < 2048) {              // ---- K fragment order ----
      const int hk = (n - 1024) >> 6;
      const int d  = (n - 1024) & 63;
      const int hh = d >> 5, qd = (d >> 3) & 3, jj = d & 7;
#pragma unroll
      for (int mi = 0; mi < 8; ++mi) {
#pragma unroll
        for (int r = 0; r < 4; ++r) {
          const int t  = crow0 + mi * 16 + r;
          const int bb = t >> 11, tt = t & 2047;
          const int kt = tt >> 6, mm = (tt >> 4) & 3, l = tt & 15;
          KF[((size_t)((bb * 16 + hk) * 32 + kt) * 8 + mm * 2 + hh) * 512 +
             (qd * 16 + l) * 8 + jj] = f2bf(acc[mi][ni][r] + bv);
        }
      }
    } else {                            // ---- V fragment order (k-perm) ----
      // R20: r=0..3 are consecutive u16.  t = crow0+mi*16+r, crow0%4==0 ->
      // to&15 = quad*4+r, so mq=to>>4 and qd2=(to>>2)&3=quad are r-invariant;
      // jj=(mq&1)*4+r consecutive; base jj%4==0 -> aligned 8B uint2 store.
      const int hv = (n - 2048) >> 6;
      const int d  = (n - 2048) & 63;
      const int di = d >> 4, l = d & 15;
#pragma unroll
      for (int mi = 0; mi < 8; ++mi) {
        const int t  = crow0 + mi * 16;          // r=0 row (t%4 == 0)
        const int bb = t >> 11, tt = t & 2047;
        const int kt = tt >> 6, to = tt & 63;
        const int mq = to >> 4, qd2 = (to >> 2) & 3;
        const int hh = mq >> 1, jj = (mq & 1) * 4;
        uint2 o;
        o.x = cvtpk(acc[mi][ni][0] + bv, acc[mi][ni][1] + bv);
        o.y = cvtpk(acc[mi][ni][2] + bv, acc[mi][ni][3] + bv);
        *(uint2*)&VF[((size_t)((bb * 16 + hv) * 32 + kt) * 8 + hh * 4 + di) * 512 +
                     (qd2 * 16 + l) * 8 + jj] = o;
      }
    }
  }
}

// ---------------- Proj GEMM: 128x64, 2 blocks/CU, 1-phase -------------------
// M=4096 N=1024 K=1024, fp32 out.  512 blocks (32 mt x 16 nt), 256 thr,
// 4 waves @ 64x32 (acc[4][2]).  LDS 2 bufs x {A0,A1,B0} = 48 KiB.
__global__ __launch_bounds__(256, 2) void gemm_proj(const u16* __restrict__ A,
                                                    const u16* __restrict__ Bt,
                                                    const float* __restrict__ bias,
                                                    float* __restrict__ C) {
  constexpr int NT = 16;                    // K=1024 / BK=64
  constexpr int BUFO = 3 * 4096;            // u16 per buffer (A0,A1,B0)
  __shared__ __align__(16) u16 sm[2 * BUFO];  // 48 KiB

  const int tid  = threadIdx.x;
  const int lane = tid & 63;
  const int w    = tid >> 6;          // 0..3
  const int quad = lane >> 4;
  const int l15  = lane & 15;

  // 512 blocks = 8 XCD x 64: each XCD 4 mt x 16 nt
  const int bid = blockIdx.x;
  const int xcd = bid & 7, c = bid >> 3;     // c 0..63
  const int mt = xcd * 4 + (c & 3);          // 0..31
  const int nt = c >> 2;                     // 0..15
  const int bm = mt * 128, bn = nt * 64;

  const int wr = (w >> 1) * 64;       // wave rows (0/64)
  const int wcC = (w & 1) * 32;       // wave cols (0/32)

  const int srow = tid >> 3;
  const int scol = (((tid & 7) ^ ((tid >> 3) & 7)) << 3);

#define PSTAGEA(ch, ktile, bufo)                                                \
  do {                                                                          \
    const u16* _s = A + (size_t)(bm + (ch) * 64 + srow) * 1024 +                \
                    ((ktile) << 6) + scol;                                      \
    u16* _d = sm + (bufo) + (ch) * 4096 + tid * 8;                              \
    __builtin_amdgcn_global_load_lds((AS1 const void*)_s, (AS3 void*)_d,        \
                                     16, 0, 0);                                 \
    __builtin_amdgcn_global_load_lds((AS1 const void*)(_s + (32 << 10)),        \
                                     (AS3 void*)(_d + 2048), 16, 0, 0);         \
  } while (0)
#define PSTAGEB(ktile, bufo)                                                    \
  do {                                                                          \
    const u16* _s = Bt + (size_t)(bn + srow) * 1024 + ((ktile) << 6) + scol;    \
    u16* _d = sm + (bufo) + 2 * 4096 + tid * 8;                                 \
    __builtin_amdgcn_global_load_lds((AS1 const void*)_s, (AS3 void*)_d,        \
                                     16, 0, 0);                                 \
    __builtin_amdgcn_global_load_lds((AS1 const void*)(_s + (32 << 10)),        \
                                     (AS3 void*)(_d + 2048), 16, 0, 0);         \
  } while (0)

  int abase[4], bbase[2];
#pragma unroll
  for (int mi = 0; mi < 4; ++mi)
    abase[mi] = (w >> 1) * 4096 + (mi * 16 + l15) * 64;
#pragma unroll
  for (int ni = 0; ni < 2; ++ni)
    bbase[ni] = 2 * 4096 + (wcC + ni * 16 + l15) * 64;
  const int sw0 = ((quad ^ (l15 & 7)) << 3);
  const int sw1 = sw0 ^ 32;

  // prologue: kt0 {A0,A1,B0} -> buf0 (6); A01(kt1) -> buf1 (4)
  PSTAGEA(0, 0, 0); PSTAGEA(1, 0, 0); PSTAGEB(0, 0);
  PSTAGEA(0, 1, BUFO); PSTAGEA(1, 1, BUFO);
  asm volatile("s_waitcnt vmcnt(4)" ::: "memory");  // kt0's 6 landed
  __builtin_amdgcn_s_barrier();

  f32x4 acc[4][2] = {};
  bf16x8 a[4][2], b[2][2];

#pragma unroll 2
  for (int j = 0; j < NT; ++j) {
    const int bo  = (j & 1) * BUFO;
    const int nbo = bo ^ BUFO;
    const u16* smb = sm + bo;

    // ---- issue ALL 12 ds_reads; stage B(j+1)->other ----
#pragma unroll
    for (int mi = 0; mi < 4; ++mi) {
      a[mi][0] = *(const bf16x8*)(smb + abase[mi] + sw0);
      a[mi][1] = *(const bf16x8*)(smb + abase[mi] + sw1);
    }
#pragma unroll
    for (int ni = 0; ni < 2; ++ni) {
      b[ni][0] = *(const bf16x8*)(smb + bbase[ni] + sw0);
      b[ni][1] = *(const bf16x8*)(smb + bbase[ni] + sw1);
    }
    if (j + 1 < NT) PSTAGEB(j + 1, nbo);

    asm volatile("s_waitcnt lgkmcnt(2)" ::: "memory");   // a + b0 landed
    __builtin_amdgcn_sched_barrier(0);
    __builtin_amdgcn_s_setprio(1);
#pragma unroll
    for (int mi = 0; mi < 4; ++mi) {
      acc[mi][0] = MFMA16(a[mi][0], b[0][0], acc[mi][0], 0, 0, 0);
      acc[mi][0] = MFMA16(a[mi][1], b[0][1], acc[mi][0], 0, 0, 0);
    }
    __builtin_amdgcn_s_setprio(0);
    asm volatile("s_waitcnt lgkmcnt(0)" ::: "memory");   // all 12 landed
    __builtin_amdgcn_sched_barrier(0);
    __builtin_amdgcn_s_barrier();     // every wave done READING buf j
    if (j + 2 < NT) { PSTAGEA(0, j + 2, bo); PSTAGEA(1, j + 2, bo); }
    __builtin_amdgcn_s_setprio(1);
#pragma unroll
    for (int mi = 0; mi < 4; ++mi) {
      acc[mi][1] = MFMA16(a[mi][0], b[1][0], acc[mi][1], 0, 0, 0);
      acc[mi][1] = MFMA16(a[mi][1], b[1][1], acc[mi][1], 0, 0, 0);
    }
    __builtin_amdgcn_s_setprio(0);
    if (j + 2 < NT)
      asm volatile("s_waitcnt vmcnt(4)" ::: "memory"); // A(j+1)+B(j+1) landed
    else
      asm volatile("s_waitcnt vmcnt(0)" ::: "memory"); // tail drain
    __builtin_amdgcn_s_barrier();
  }
#undef PSTAGEA
#undef PSTAGEB

  const int crow0 = bm + wr + (quad << 2);
  const int ccol0 = bn + wcC + l15;
#pragma unroll
  for (int ni = 0; ni < 2; ++ni) {
    const int n = ccol0 + ni * 16;
    const float bv = bias[n];
#pragma unroll
    for (int mi = 0; mi < 4; ++mi) {
      const int m0 = crow0 + mi * 16;
#pragma unroll
      for (int r = 0; r < 4; ++r)
        C[(size_t)(m0 + r) * 1024 + n] = acc[mi][ni][r] + bv;
    }
  }
}

// ---------------- uniform-wave pipelined MFMA flash attention ---------------
// grid 1024 x 128 threads.  bid: xcd = bid&7 (4 bh per XCD, KV L2-resident);
// c = bid>>3: u = c&31 (q-group pair), bh = xcd | ((c>>5)<<3).
// Each wave: q-group 63-u fully, then q-group u (accO reused between groups).
// Parity waves split kt; per-wave total = 16-17 tiles UNIFORMLY across the
// whole grid -> 2 waves/SIMD resident for the entire kernel, no decay.
// K AND V prefetched depth-2 (kA/kB, vA/vB static ping-pong).
__global__ __launch_bounds__(128, 2) void attn_bal(const u16* __restrict__ qb,
                                                   const u16* __restrict__ KF,
                                                   const u16* __restrict__ VF,
                                                   u16* __restrict__ out) {
  const int bid = blockIdx.x;
  const int c   = bid >> 3;
  const int u   = c & 31;
  const int bh  = (bid & 7) | ((c >> 5) << 3);
  const int b = bh >> 4, h = bh & 15;
  const int tid = threadIdx.x;
  const int lane = tid & 63;
  const int par  = tid >> 6;          // wave 0/1 = kt parity
  const int quad = lane >> 4;
  const int l15  = lane & 15;

  __shared__ float CB[64][41];        // [lane][32 accO + 8 accL], stride 41

  const u16* qbase = qb + (size_t)b * 2048 * 1024 + h * 64;
  const size_t fb = (size_t)bh * 32 * 4096 + lane * 8;
  const u16* kfb = KF + fb;
  const u16* vfb = VF + fb;

  union { u32 u4[4]; bf16x8 v; } onesu;
  onesu.u4[0] = onesu.u4[1] = onesu.u4[2] = onesu.u4[3] = 0x3f803f80u;
  const bf16x8 onesf = onesu.v;       // bf16 1.0 x8

  u16* const outb = out + (size_t)b * 2048 * 1024 + h * 64 + l15;

  auto run_group = [&](int g32) {
    const int q0 = g32 * 32;
    const int ktmax = g32 >> 1;

    // Q B-frags for this group
    bf16x8 qf[2][2];
#pragma unroll
    for (int g = 0; g < 2; ++g)
#pragma unroll
      for (int hh = 0; hh < 2; ++hh)
        qf[g][hh] = *(const bf16x8*)(qbase + (size_t)(q0 + g * 16 + l15) * 1024 +
                                     hh * 32 + quad * 8);

    f32x4 accO[2][4] = {};            // [g][di]: q=quad*4+r, d=di*16+l15
    f32x4 accL[2] = {};               // [g]: l for q=quad*4+r

    // depth-2 K+V pipeline, two register sets (static ping-pong, no rotate)
    bf16x8 kA[4][2], kB[4][2], vA[2][4], vB[2][4];
    {
      const u16* kp = kfb + (size_t)par * 4096;
      const u16* vp = vfb + (size_t)par * 4096;
#pragma unroll
      for (int m = 0; m < 4; ++m)
#pragma unroll
        for (int hh = 0; hh < 2; ++hh)
          kA[m][hh] = *(const bf16x8*)(kp + (m * 2 + hh) * 512);
#pragma unroll
      for (int hh = 0; hh < 2; ++hh)
#pragma unroll
        for (int di = 0; di < 4; ++di)
          vA[hh][di] = *(const bf16x8*)(vp + (hh * 4 + di) * 512);
    }

    auto tile = [&](int kt, bf16x8 (&KC)[4][2], bf16x8 (&KN)[4][2],
                    bf16x8 (&VC)[2][4], bf16x8 (&VN)[2][4]) {
      // prefetch kt+2 (clamped) into the other register set
      const int ktn = (kt + 2 <= ktmax) ? kt + 2 : ktmax;
      const u16* kpn = kfb + (size_t)ktn * 4096;
      const u16* vpn = vfb + (size_t)ktn * 4096;
#pragma unroll
      for (int m = 0; m < 4; ++m)
#pragma unroll
        for (int hh = 0; hh < 2; ++hh)
          KN[m][hh] = *(const bf16x8*)(kpn + (m * 2 + hh) * 512);
#pragma unroll
      for (int hh = 0; hh < 2; ++hh)
#pragma unroll
        for (int di = 0; di < 4; ++di)
          VN[hh][di] = *(const bf16x8*)(vpn + (hh * 4 + di) * 512);

      const bool diag = (kt == ktmax);
      bf16x8 ap[2][2];
#pragma unroll
      for (int g = 0; g < 2; ++g) {
        f32x4 sT[4] = {};
#pragma unroll
        for (int m = 0; m < 4; ++m) {
          sT[m] = MFMA16(KC[m][0], qf[g][0], sT[m], 0, 0, 0);
          sT[m] = MFMA16(KC[m][1], qf[g][1], sT[m], 0, 0, 0);
        }
        float pv[4][4];
        if (diag) {                    // only the last tile pays mask ops
          const int qgl = q0 + g * 16 + l15;
#pragma unroll
          for (int m = 0; m < 4; ++m)
#pragma unroll
            for (int r = 0; r < 4; ++r) {
              const bool msk = (kt * 64 + m * 16 + quad * 4 + r) > qgl;
              pv[m][r] = msk ? 0.f : __builtin_amdgcn_exp2f(sT[m][r]);
            }
        } else {
#pragma unroll
          for (int m = 0; m < 4; ++m)
#pragma unroll
            for (int r = 0; r < 4; ++r)
              pv[m][r] = __builtin_amdgcn_exp2f(sT[m][r]);
        }
        union { u32 u4[4]; bf16x8 v; } t0, t1;
        t0.u4[0] = cvtpk(pv[0][0], pv[0][1]);
        t0.u4[1] = cvtpk(pv[0][2], pv[0][3]);
        t0.u4[2] = cvtpk(pv[1][0], pv[1][1]);
        t0.u4[3] = cvtpk(pv[1][2], pv[1][3]);
        t1.u4[0] = cvtpk(pv[2][0], pv[2][1]);
        t1.u4[1] = cvtpk(pv[2][2], pv[2][3]);
        t1.u4[2] = cvtpk(pv[3][0], pv[3][1]);
        t1.u4[3] = cvtpk(pv[3][2], pv[3][3]);
        ap[g][0] = t0.v;
        ap[g][1] = t1.v;
      }

      // O += P.V
#pragma unroll
      for (int hh = 0; hh < 2; ++hh)
#pragma unroll
        for (int di = 0; di < 4; ++di) {
          bf16x8 bv = VC[hh][di];
#pragma unroll
          for (int g = 0; g < 2; ++g)
            accO[g][di] = MFMA16(ap[g][hh], bv, accO[g][di], 0, 0, 0);
        }
      // l += P.1 (MFMA does the cross-quad k-reduction)
#pragma unroll
      for (int g = 0; g < 2; ++g) {
        accL[g] = MFMA16(ap[g][0], onesf, accL[g], 0, 0, 0);
        accL[g] = MFMA16(ap[g][1], onesf, accL[g], 0, 0, 0);
      }
    };

    for (int kt = par; kt <= ktmax; ) {
      tile(kt, kA, kB, vA, vB); kt += 2;
      if (kt > ktmax) break;
      tile(kt, kB, kA, vB, vA); kt += 2;
    }

    // ---- exact parity combine (per-lane values) ----
    if (par) {
      float* cb = CB[lane];
#pragma unroll
      for (int g = 0; g < 2; ++g) {
#pragma unroll
        for (int di = 0; di < 4; ++di)
#pragma unroll
          for (int r = 0; r < 4; ++r)
            cb[g * 16 + di * 4 + r] = accO[g][di][r];
#pragma unroll
        for (int r = 0; r < 4; ++r)
          cb[32 + g * 4 + r] = accL[g][r];
      }
    }
    __syncthreads();
    if (!par) {
      const float* cb = CB[lane];
#pragma unroll
      for (int g = 0; g < 2; ++g) {
#pragma unroll
        for (int di = 0; di < 4; ++di)
#pragma unroll
          for (int r = 0; r < 4; ++r)
            accO[g][di][r] += cb[g * 16 + di * 4 + r];
#pragma unroll
        for (int r = 0; r < 4; ++r)
          accL[g][r] += cb[32 + g * 4 + r];
      }
#pragma unroll
      for (int g = 0; g < 2; ++g)
#pragma unroll
        for (int r = 0; r < 4; ++r) {
          const float inv = 1.f / accL[g][r]; // lane holds l for its own rows
          const int q = q0 + g * 16 + quad * 4 + r;
          u16* op = outb + (size_t)q * 1024;
#pragma unroll
          for (int di = 0; di < 4; ++di)
            op[di * 16] = f2bf(accO[g][di][r] * inv);
        }
    }
    __syncthreads();   // CB safe for reuse by the next group
  };

  run_group(63 - u);   // heavy half
  run_group(u);        // light half -> every wave totals 16-17 tiles
}

// ---------------------------------------------------------------------------
extern "C" void kernel_launch(void* const* d_in, const int* in_sizes, int n_in,
                              void* d_out, int out_size, void* d_ws, size_t ws_size,
                              hipStream_t stream) {
  const float* x     = (const float*)d_in[0];
  const float* Wqkv  = (const float*)d_in[1];
  const float* bqkv  = (const float*)d_in[2];
  const float* Wproj = (const float*)d_in[3];
  const float* bproj = (const float*)d_in[4];
  float* out = (float*)d_out;

  char* ws = (char*)d_ws;
  u16* xb     = (u16*)(ws);                 //  8 MB  x bf16 [4096,1024]
  u16* wqkvT  = (u16*)(ws + 8388608);       //  6 MB  Wqkv^T bf16 [3072,1024]
  u16* wprojT = (u16*)(ws + 14680064);      //  2 MB  Wproj^T bf16 [1024,1024]
  u16* qb     = (u16*)(ws + 16777216);      //  8 MB  Q bf16 [4096,1024] (pre-scaled)
  u16* KF     = (u16*)(ws + 25165824);      //  8 MB  K fragment-order
  u16* VF     = (u16*)(ws + 33554432);      //  8 MB  V fragment-order (k-perm)
  u16* att    = (u16*)(ws + 41943040);      //  8 MB  attn out bf16 [4096,1024]

  constexpr float cs = 0.18033688011f;      // log2(e)/8

  prep<<<8192, 256, 0, stream>>>(x, xb, Wqkv, wqkvT, Wproj, wprojT);

  gemm_qkv<<<dim3(512), 256, 0, stream>>>(xb, wqkvT, bqkv, qb, KF, VF, cs);

  attn_bal<<<dim3(1024), 128, 0, stream>>>(qb, KF, VF, att);

  gemm_proj<<<dim3(512), 256, 0, stream>>>(att, wprojT, bproj, out);
}